// Round 1
// baseline (584.983 us; speedup 1.0000x reference)
//
#include <hip/hip_runtime.h>
#include <hip/hip_bf16.h>
#include <cstdint>

#define N_HEAD 16
#define HEAD_DIM 128

typedef __bf16 bf16;
typedef __bf16 bf16x8 __attribute__((ext_vector_type(8)));
typedef __bf16 bf16x4 __attribute__((ext_vector_type(4)));
typedef float f32x4 __attribute__((ext_vector_type(4)));

// async global->LDS 16B (per-lane lds addr must be base + lane*16)
__device__ __forceinline__ void gload_lds16(const void* g, void* l) {
  auto gp = reinterpret_cast<const __attribute__((address_space(1))) char*>(
      reinterpret_cast<uintptr_t>(g));
  auto lp = reinterpret_cast<__attribute__((address_space(3))) char*>(
      reinterpret_cast<uintptr_t>(l));
  __builtin_amdgcn_global_load_lds(gp, lp, 16, 0, 0);
}

// ---------------- fp32 -> bf16 convert (vectorized) ----------------
__global__ __launch_bounds__(256) void cvt_bf16(const float* __restrict__ in,
                                                bf16* __restrict__ out, int n4) {
  int i = blockIdx.x * 256 + threadIdx.x;
  if (i >= n4) return;
  const float4 f = reinterpret_cast<const float4*>(in)[i];
  bf16x4 o;
  o.x = (bf16)f.x; o.y = (bf16)f.y; o.z = (bf16)f.z; o.w = (bf16)f.w;
  reinterpret_cast<bf16x4*>(out)[i] = o;
}

// ---------------- GEMM: C[M,N] = A[M,K] * B[N,K]^T (both row-major, bf16) ----
// 128x128 tile, BK=32, 4 waves (2x2 of 64x64), 16x16x32 bf16 MFMA.
template <typename OutT>
__global__ __launch_bounds__(256) void gemm_bt(
    const bf16* __restrict__ A, const bf16* __restrict__ Bt,
    OutT* __restrict__ C, int M, int N, int K) {
  __shared__ __align__(16) bf16 As[128 * 32];
  __shared__ __align__(16) bf16 Bs[128 * 32];
  const int tid = threadIdx.x;
  const int lane = tid & 63;
  const int wave = tid >> 6;
  const int wm = (wave >> 1) * 64;
  const int wn = (wave & 1) * 64;
  const int lr = lane & 15;
  const int lk = (lane >> 4) * 8;

  const bf16* Ab = A + (size_t)blockIdx.y * 128 * K;
  const bf16* Bb = Bt + (size_t)blockIdx.x * 128 * K;

  const int r0 = tid >> 2;        // 0..63, +64 on second pass
  const int c0 = (tid & 3) * 8;   // k-offset in elements

  f32x4 acc[4][4] = {};

  for (int k0 = 0; k0 < K; k0 += 32) {
    __syncthreads();
    gload_lds16(Ab + (size_t)r0 * K + k0 + c0, As + (size_t)tid * 8);
    gload_lds16(Ab + (size_t)(r0 + 64) * K + k0 + c0, As + (size_t)(256 + tid) * 8);
    gload_lds16(Bb + (size_t)r0 * K + k0 + c0, Bs + (size_t)tid * 8);
    gload_lds16(Bb + (size_t)(r0 + 64) * K + k0 + c0, Bs + (size_t)(256 + tid) * 8);
    __syncthreads();

    bf16x8 a[4], b[4];
#pragma unroll
    for (int i = 0; i < 4; ++i)
      a[i] = *reinterpret_cast<const bf16x8*>(As + (wm + i * 16 + lr) * 32 + lk);
#pragma unroll
    for (int j = 0; j < 4; ++j)
      b[j] = *reinterpret_cast<const bf16x8*>(Bs + (wn + j * 16 + lr) * 32 + lk);
#pragma unroll
    for (int i = 0; i < 4; ++i)
#pragma unroll
      for (int j = 0; j < 4; ++j)
        acc[i][j] = __builtin_amdgcn_mfma_f32_16x16x32_bf16(a[i], b[j], acc[i][j], 0, 0, 0);
  }

  const int orow = blockIdx.y * 128 + wm + (lane >> 4) * 4;
  const int ocol = blockIdx.x * 128 + wn + lr;
#pragma unroll
  for (int i = 0; i < 4; ++i)
#pragma unroll
    for (int j = 0; j < 4; ++j)
#pragma unroll
      for (int r = 0; r < 4; ++r)
        C[(size_t)(orow + i * 16 + r) * N + (ocol + j * 16)] = (OutT)acc[i][j][r];
}

// ---------------- rope + rms-norm, in-place on q and k (bf16) ---------------
// grid: (B*T, H/4, 2[q|k]); one wave per head; lane i handles pair (i, i+64)
__global__ __launch_bounds__(256) void rope_rms(
    bf16* __restrict__ q, bf16* __restrict__ k,
    const float* __restrict__ cs, const float* __restrict__ sn, int T) {
  const int bt = blockIdx.x;
  const int t = bt % T;
  const int wave = threadIdx.x >> 6;
  const int lane = threadIdx.x & 63;
  const int h = blockIdx.y * 4 + wave;
  bf16* p = (blockIdx.z ? k : q) + (size_t)bt * (N_HEAD * HEAD_DIM) + h * HEAD_DIM;
  const float c = cs[t * 64 + lane];
  const float s = sn[t * 64 + lane];
  const float x1 = (float)p[lane];
  const float x2 = (float)p[lane + 64];
  const float r1 = x1 * c + x2 * s;
  const float r2 = x2 * c - x1 * s;
  float ss = r1 * r1 + r2 * r2;
#pragma unroll
  for (int m = 1; m < 64; m <<= 1) ss += __shfl_xor(ss, m);
  const float sc = 1.2f * rsqrtf(ss * (1.0f / 128.0f) + 1e-6f);
  p[lane] = (bf16)(r1 * sc);
  p[lane + 64] = (bf16)(r2 * sc);
}

// ---------------- v += 3*sigmoid(x[:12] @ Wg^T) * ve, in-place (bf16) -------
__global__ __launch_bounds__(256) void v_gate(
    bf16* __restrict__ v, const float* __restrict__ x,
    const float* __restrict__ ve, const float* __restrict__ Wg, int C) {
  const int bt = blockIdx.x;
  __shared__ float g[N_HEAD];
  if (threadIdx.x < N_HEAD) {
    const float* xr = x + (size_t)bt * C;
    float a = 0.f;
#pragma unroll
    for (int j = 0; j < 12; ++j) a += xr[j] * Wg[threadIdx.x * 12 + j];
    g[threadIdx.x] = 3.f / (1.f + __expf(-a));
  }
  __syncthreads();
  const size_t base = (size_t)bt * C;
  const int c0 = threadIdx.x * 8;
  const float gh = g[c0 >> 7];
#pragma unroll
  for (int i = 0; i < 8; ++i) {
    const int c = c0 + i;
    v[base + c] = (bf16)((float)v[base + c] + gh * ve[base + c]);
  }
}

// ---------------- flash attention, sliding window -------------------------
// grid: (T/64, H, B); 4 waves x 16 q-rows; keys in chunks of 32.
__global__ __launch_bounds__(256) void attn(
    const bf16* __restrict__ q, const bf16* __restrict__ k,
    const bf16* __restrict__ v, bf16* __restrict__ y,
    const int* __restrict__ wptr, int T) {
  const int C = N_HEAD * HEAD_DIM;
  const int qb = blockIdx.x * 64;
  const int h = blockIdx.y;
  const int b = blockIdx.z;
  const int wave = threadIdx.x >> 6;
  const int lane = threadIdx.x & 63;
  const int lm = lane & 15;
  const int quad = lane >> 4;

  const int w = wptr[0];
  const int W = (w > 0 && w < T) ? w : (1 << 30);

  __shared__ __align__(16) bf16 Vt[128][40];   // [d][key], padded rows (80B)
  __shared__ __align__(16) bf16 P[4][16][40];  // per-wave P[q][key], padded

  const size_t bh = (size_t)b * T * C + (size_t)h * HEAD_DIM;
  const bf16* kb = k + bh;
  const bf16* vb = v + bh;

  const int qg0 = qb + wave * 16;
  const bf16* qrow = q + bh + (size_t)(qg0 + lm) * C;
  bf16x8 qf[4];
#pragma unroll
  for (int c = 0; c < 4; ++c)
    qf[c] = *reinterpret_cast<const bf16x8*>(qrow + c * 32 + quad * 8);

  float mrun[4], lrun[4];
#pragma unroll
  for (int r = 0; r < 4; ++r) { mrun[r] = -1e30f; lrun[r] = 0.f; }
  f32x4 oacc[8] = {};

  int kstart = qb - W;
  if (kstart < 0) kstart = 0;
  kstart &= ~31;
  const int kend = qb + 63;

  const int sr = threadIdx.x >> 3;         // staging: key 0..31
  const int sc0 = (threadIdx.x & 7) * 16;  // staging: d offset

  const float scale = 0.08838834764831845f;  // 1/sqrt(128)

  for (int kc = kstart; kc <= kend; kc += 32) {
    __syncthreads();
    {  // stage V chunk transposed into LDS
      int key = kc + sr;
      if (key >= T) key = T - 1;
      const bf16* vr = vb + (size_t)key * C + sc0;
      bf16x8 t0 = *reinterpret_cast<const bf16x8*>(vr);
      bf16x8 t1 = *reinterpret_cast<const bf16x8*>(vr + 8);
#pragma unroll
      for (int i = 0; i < 8; ++i) Vt[sc0 + i][sr] = t0[i];
#pragma unroll
      for (int i = 0; i < 8; ++i) Vt[sc0 + 8 + i][sr] = t1[i];
    }
    // S = Q K^T for 16 q-rows x 32 keys
    f32x4 s[2] = {};
#pragma unroll
    for (int g = 0; g < 2; ++g) {
      int key = kc + g * 16 + lm;
      if (key >= T) key = T - 1;
      const bf16* kr = kb + (size_t)key * C;
#pragma unroll
      for (int c = 0; c < 4; ++c) {
        bf16x8 kf = *reinterpret_cast<const bf16x8*>(kr + c * 32 + quad * 8);
        s[g] = __builtin_amdgcn_mfma_f32_16x16x32_bf16(qf[c], kf, s[g], 0, 0, 0);
      }
    }
    // mask + online softmax (each lane owns rows quad*4+r, col lm / 16+lm)
#pragma unroll
    for (int r = 0; r < 4; ++r) {
      const int qr = qg0 + quad * 4 + r;
#pragma unroll
      for (int g = 0; g < 2; ++g) {
        const int kg = kc + g * 16 + lm;
        const bool valid = (kg <= qr) && (qr - kg <= W);
        s[g][r] = valid ? s[g][r] * scale : -1e30f;
      }
      float mx = fmaxf(s[0][r], s[1][r]);
#pragma unroll
      for (int off = 1; off < 16; off <<= 1) mx = fmaxf(mx, __shfl_xor(mx, off));
      const float mnew = fmaxf(mrun[r], mx);
      const float alpha = __expf(mrun[r] - mnew);
      mrun[r] = mnew;
      const float p0 = (s[0][r] < -1e29f) ? 0.f : __expf(s[0][r] - mnew);
      const float p1 = (s[1][r] < -1e29f) ? 0.f : __expf(s[1][r] - mnew);
      float rs = p0 + p1;
#pragma unroll
      for (int off = 1; off < 16; off <<= 1) rs += __shfl_xor(rs, off);
      lrun[r] = lrun[r] * alpha + rs;
#pragma unroll
      for (int dc = 0; dc < 8; ++dc) oacc[dc][r] *= alpha;
      P[wave][quad * 4 + r][lm] = (bf16)p0;
      P[wave][quad * 4 + r][16 + lm] = (bf16)p1;
    }
    __syncthreads();
    // O += P V  (P: A-layout from LDS; V^T: B-layout from LDS)
    const bf16x8 pf = *reinterpret_cast<const bf16x8*>(&P[wave][lm][quad * 8]);
#pragma unroll
    for (int dc = 0; dc < 8; ++dc) {
      bf16x8 vf = *reinterpret_cast<const bf16x8*>(&Vt[dc * 16 + lm][quad * 8]);
      oacc[dc] = __builtin_amdgcn_mfma_f32_16x16x32_bf16(pf, vf, oacc[dc], 0, 0, 0);
    }
  }

  bf16* yr = y + bh + (size_t)(qg0 + quad * 4) * C + lm;
#pragma unroll
  for (int r = 0; r < 4; ++r) {
    const float inv = 1.f / lrun[r];
#pragma unroll
    for (int dc = 0; dc < 8; ++dc)
      yr[(size_t)r * C + dc * 16] = (bf16)(oacc[dc][r] * inv);
  }
}

extern "C" void kernel_launch(void* const* d_in, const int* in_sizes, int n_in,
                              void* d_out, int out_size, void* d_ws, size_t ws_size,
                              hipStream_t stream) {
  const float* x  = (const float*)d_in[0];
  const float* ve = (const float*)d_in[1];
  const float* Wq = (const float*)d_in[2];
  const float* Wk = (const float*)d_in[3];
  const float* Wv = (const float*)d_in[4];
  const float* Wp = (const float*)d_in[5];
  const float* Wg = (const float*)d_in[6];
  const float* cs = (const float*)d_in[7];
  const float* sn = (const float*)d_in[8];
  const int*   wl = (const int*)d_in[9];
  float* out = (float*)d_out;

  const int C = N_HEAD * HEAD_DIM;       // 2048
  const int T = in_sizes[7] / (HEAD_DIM / 2);
  const int B = in_sizes[0] / (T * C);
  const int M = B * T;

  bf16* xb   = (bf16*)d_ws;
  bf16* wqb  = xb  + (size_t)M * C;
  bf16* wkb  = wqb + (size_t)C * C;
  bf16* wvb  = wkb + (size_t)C * C;
  bf16* wpb  = wvb + (size_t)C * C;
  bf16* qbuf = wpb + (size_t)C * C;
  bf16* kbuf = qbuf + (size_t)M * C;
  bf16* vbuf = kbuf + (size_t)M * C;
  bf16* ybuf = vbuf + (size_t)M * C;

  const int nx4 = M * C / 4, nw4 = C * C / 4;
  cvt_bf16<<<(nx4 + 255) / 256, 256, 0, stream>>>(x, xb, nx4);
  cvt_bf16<<<(nw4 + 255) / 256, 256, 0, stream>>>(Wq, wqb, nw4);
  cvt_bf16<<<(nw4 + 255) / 256, 256, 0, stream>>>(Wk, wkb, nw4);
  cvt_bf16<<<(nw4 + 255) / 256, 256, 0, stream>>>(Wv, wvb, nw4);
  cvt_bf16<<<(nw4 + 255) / 256, 256, 0, stream>>>(Wp, wpb, nw4);

  dim3 gg(C / 128, M / 128);
  gemm_bt<bf16><<<gg, 256, 0, stream>>>(xb, wqb, qbuf, M, C, C);
  gemm_bt<bf16><<<gg, 256, 0, stream>>>(xb, wkb, kbuf, M, C, C);
  gemm_bt<bf16><<<gg, 256, 0, stream>>>(xb, wvb, vbuf, M, C, C);

  rope_rms<<<dim3(M, N_HEAD / 4, 2), 256, 0, stream>>>(qbuf, kbuf, cs, sn, T);
  v_gate<<<M, 256, 0, stream>>>(vbuf, x, ve, Wg, C);
  attn<<<dim3(T / 64, N_HEAD, B), 256, 0, stream>>>(qbuf, kbuf, vbuf, ybuf, wl, T);

  gemm_bt<float><<<gg, 256, 0, stream>>>(ybuf, wpb, out, M, C, C);
}